// Round 11
// baseline (371.278 us; speedup 1.0000x reference)
//
#include <hip/hip_runtime.h>
#include <cstdint>

// ---------------------------------------------------------------------------
// RegionModel R11: async global->LDS staging via __builtin_amdgcn_global_load_lds.
// R10's conv3 was staging-latency-bound (HBM 17%, occ 21%: per-thread
// 4-load/waitcnt/4-ds_write rounds + exactly 2 blocks/CU in ONE round -> no
// overlap anywhere). R11: staging = global_load_lds width 16 (HW DMA, no VGPR
// round trip, ~19 async issues per wave, one drain at the barrier); the
// [row][x][c8] -> [row][c8][x] transpose moved into per-lane global addresses
// (LDS side must be base + lane*16). conv3 re-tiled to 4 out rows / 128 thr /
// 38 KB phase tile -> 4 blocks/CU, 1024 blocks (cross-block overlap), GAP
// epilogue LDS-combined -> 1 coalesced atomic per oc. imgcvt vectorized.
// ---------------------------------------------------------------------------

typedef __attribute__((ext_vector_type(8))) short short8;
typedef __attribute__((ext_vector_type(4))) float floatx4;
typedef __attribute__((ext_vector_type(4))) unsigned short ushort4v;
typedef __attribute__((ext_vector_type(4))) float float4v;

__device__ inline unsigned short f2bf(float f) {
  union { float f; unsigned u; } x;
  x.f = f;
  unsigned u = x.u;
  u += 0x7FFFu + ((u >> 16) & 1u);  // round-to-nearest-even
  return (unsigned short)(u >> 16);
}

// Async 16B global->LDS DMA. LDS dest (wave-uniform base) + lane*16.
// Generic LDS pointer's low 32 bits == LDS offset (shared aperture is in the
// high bits), so truncation yields a valid AS(3) pointer (CK-style).
__device__ inline void g2l16(const unsigned short* g, unsigned short* l) {
  __builtin_amdgcn_global_load_lds(
      (const __attribute__((address_space(1))) unsigned int*)g,
      (__attribute__((address_space(3))) unsigned int*)(unsigned int)(uintptr_t)l,
      16, 0, 0);
}

__global__ __launch_bounds__(128) void prep_k(const int* __restrict__ rp,
                                              int* __restrict__ rout,
                                              float* __restrict__ feat) {
  __shared__ int is64;
  if (threadIdx.x == 0) {
    int odd_or = 0;
    for (int i = 0; i < 64; ++i) odd_or |= rp[2 * i + 1];
    is64 = (odd_or == 0) ? 1 : 0;
  }
  __syncthreads();
  int b = threadIdx.x;
  int r = is64 ? rp[2 * b] : rp[b];
  rout[b] = r & 7;
  float* fr = feat + b * 128;
  for (int j = 0; j < 128; ++j) fr[j] = 0.f;
}

// conv1 weights -> [r][kg(2)][mt(2)][lane][j] ; k = kg*32+q*8+j maps to
// row = kg*2+(q>>1), idx=(q&1)*8+j, kx=idx>>2, c=idx&3; pad slots -> 0.
__global__ __launch_bounds__(256) void pack1_k(const float* __restrict__ w,
                                               unsigned short* __restrict__ dst) {
  int t = blockIdx.x * blockDim.x + threadIdx.x;
  if (t >= 16384) return;
  int j = t & 7, lane = (t >> 3) & 63, mt = (t >> 9) & 1, kg = (t >> 10) & 1,
      r = t >> 11;
  int oc = mt * 16 + (lane & 15);
  int q = (lane >> 4) & 3;
  int row = kg * 2 + (q >> 1);
  int idx = (q & 1) * 8 + j;
  int kx = idx >> 2, c = idx & 3;
  float val = 0.f;
  if (row < 3 && kx < 3 && c < 3) val = w[((r * 32 + oc) * 3 + c) * 9 + row * 3 + kx];
  dst[t] = f2bf(val);
}

// conv2/3 weights [R][OC][IC][3][3] -> [r][tap][s][mt][lane][j], ic=s*32+q*8+j
template <int OC, int IC, int SUBK, int MTG>
__global__ __launch_bounds__(256) void packT_k(const float* __restrict__ w,
                                               unsigned short* __restrict__ dst) {
  const int total = 8 * 9 * SUBK * MTG * 512;
  int t = blockIdx.x * blockDim.x + threadIdx.x;
  if (t >= total) return;
  int j = t & 7, lane = (t >> 3) & 63;
  int u = t >> 9;
  int mt = u % MTG; u /= MTG;
  int s = u % SUBK; u /= SUBK;
  int tap = u % 9;
  int r = u / 9;
  int oc = mt * 16 + (lane & 15);
  int ic = s * 32 + ((lane >> 4) & 3) * 8 + j;
  dst[t] = f2bf(w[((r * OC + oc) * IC + ic) * 9 + tap]);
}

// fp32 planar image -> padded c-last bf16 interior [s][258][258][4].
// One thread = 4 interior pixels along x: 3x float4 reads, 4x 8B writes.
__global__ __launch_bounds__(256) void imgcvt_k(const float* __restrict__ img,
                                                unsigned short* __restrict__ dst,
                                                int b0) {
  int idx = blockIdx.x * 256 + threadIdx.x;  // 0..16383 per sample
  int y = idx >> 6, xq = idx & 63;
  int s = blockIdx.y;
  const float* ip = img + ((size_t)(b0 + s) * 3) * 65536 + y * 256 + xq * 4;
  float4v a = *(const float4v*)ip;
  float4v bb = *(const float4v*)(ip + 65536);
  float4v cc = *(const float4v*)(ip + 131072);
  unsigned short* dp =
      dst + ((size_t)s * 258 * 258 + (size_t)(y + 1) * 258 + xq * 4 + 1) * 4;
#pragma unroll
  for (int i = 0; i < 4; ++i) {
    ushort4v v = {f2bf(a[i]), f2bf(bb[i]), f2bf(cc[i]), 0};
    *(ushort4v*)(dp + i * 4) = v;
  }
}

// zero halo of padded image buffer [nsamp][258][258][4]
__global__ __launch_bounds__(256) void halo4_k(unsigned short* __restrict__ buf,
                                               int nsamp) {
  const int per = 2 * 258 + 2 * 256;
  int t = blockIdx.x * blockDim.x + threadIdx.x;
  if (t >= nsamp * per) return;
  int s = t / per, i = t - s * per;
  int y, x;
  if (i < 258) { y = 0; x = i; }
  else if (i < 516) { y = 257; x = i - 258; }
  else {
    int ii = i - 516;
    y = 1 + (ii >> 1);
    x = (ii & 1) ? 257 : 0;
  }
  ushort4v z = {0, 0, 0, 0};
  *(ushort4v*)(buf + ((size_t)s * 258 * 258 + y * 258 + x) * 4) = z;
}

// zero halo of channels-last buffer [nsamp][HP][WP][IC], IC multiple of 8
template <int IC>
__global__ __launch_bounds__(256) void haloc_k(unsigned short* __restrict__ buf,
                                               int nsamp, int HP, int WP) {
  int per = 2 * WP + 2 * (HP - 2);
  int t = blockIdx.x * blockDim.x + threadIdx.x;
  if (t >= nsamp * per) return;
  int s = t / per, i = t - s * per;
  int y, x;
  if (i < WP) { y = 0; x = i; }
  else if (i < 2 * WP) { y = HP - 1; x = i - WP; }
  else {
    int ii = i - 2 * WP;
    y = 1 + (ii >> 1);
    x = (ii & 1) ? (WP - 1) : 0;
  }
  unsigned short* p = buf + ((size_t)s * HP * WP + y * WP + x) * IC;
  short8 z = {0, 0, 0, 0, 0, 0, 0, 0};
#pragma unroll
  for (int j = 0; j < IC / 8; ++j) ((short8*)p)[j] = z;
}

// conv1: 3->32, 256->128. imgp [258][258][4] c-last, K = 3 rows x 16.
// Wave = 64 px (4 n-tiles of 16), B loads batched. (unchanged from R10)
__global__ __launch_bounds__(256, 4) void conv1_k(
    const unsigned short* __restrict__ in, const unsigned short* __restrict__ wp,
    const float* __restrict__ bias, const int* __restrict__ rgn,
    unsigned short* __restrict__ outp, int b0) {
  const int tid = threadIdx.x;
  const int bl = blockIdx.y;
  const int r = __builtin_amdgcn_readfirstlane(rgn[b0 + bl]);
  __shared__ float sBias[32];
  if (tid < 32) sBias[tid] = bias[r * 32 + tid];
  __syncthreads();
  const int n = tid & 15, q = (tid >> 4) & 3;
  const int lane = tid & 63;
  const int px0 = (blockIdx.x * 4 + (tid >> 6)) * 64;
  const unsigned short* inb = in + (size_t)bl * 258 * 258 * 4 + (q & 1) * 8;
  int oyA[4], oxA[4];
  const unsigned short* pB[4];
#pragma unroll
  for (int nt = 0; nt < 4; ++nt) {
    int px = px0 + nt * 16 + n;
    oyA[nt] = px >> 7;
    oxA[nt] = px & 127;
    pB[nt] = inb + ((size_t)(2 * oyA[nt]) * 258 + 2 * oxA[nt]) * 4;
  }
  const short8* wpb = (const short8*)wp + (size_t)r * 256 + lane;
  short8 bfr[2][4];
#pragma unroll
  for (int kg = 0; kg < 2; ++kg) {
    int row = kg * 2 + (q >> 1);
    int rowc = (row < 3) ? row : 0;  // pad rows: zero weights, safe addr
#pragma unroll
    for (int nt = 0; nt < 4; ++nt)
      bfr[kg][nt] = *(const short8*)(pB[nt] + (size_t)rowc * 258 * 4);
  }
  short8 afr[2][2];
#pragma unroll
  for (int kg = 0; kg < 2; ++kg)
#pragma unroll
    for (int m = 0; m < 2; ++m) afr[kg][m] = wpb[(kg * 2 + m) * 64];
  floatx4 acc[4][2];
#pragma unroll
  for (int nt = 0; nt < 4; ++nt)
#pragma unroll
    for (int m = 0; m < 2; ++m) acc[nt][m] = (floatx4){0.f, 0.f, 0.f, 0.f};
#pragma unroll
  for (int kg = 0; kg < 2; ++kg)
#pragma unroll
    for (int m = 0; m < 2; ++m)
#pragma unroll
      for (int nt = 0; nt < 4; ++nt)
        acc[nt][m] = __builtin_amdgcn_mfma_f32_16x16x32_bf16(afr[kg][m], bfr[kg][nt],
                                                             acc[nt][m], 0, 0, 0);
  unsigned short* ob = outp + (size_t)bl * 130 * 130 * 32;
#pragma unroll
  for (int nt = 0; nt < 4; ++nt)
#pragma unroll
    for (int m = 0; m < 2; ++m) {
      ushort4v st;
#pragma unroll
      for (int rr = 0; rr < 4; ++rr) {
        float v = acc[nt][m][rr] + sBias[m * 16 + q * 4 + rr];
        st[rr] = f2bf(v > 0.f ? v : 0.f);
      }
      *(ushort4v*)(ob + ((size_t)(oyA[nt] + 1) * 130 + oxA[nt] + 1) * 32 + m * 16 +
                   q * 4) = st;
    }
}

// conv2: 32->64, 64x64 out. Block = 4 out rows x 64 px; wave w = row oy0+w.
// LDS tile [row][c8][x][8ch] staged via global_load_lds (slot c = lane order;
// transpose folded into per-lane global address). K-loop from LDS.
__global__ __launch_bounds__(256, 2) void conv2lds_k(
    const unsigned short* __restrict__ in, const unsigned short* __restrict__ wp,
    const float* __restrict__ bias, const int* __restrict__ rgn,
    unsigned short* __restrict__ outp, int b0) {
  __shared__ unsigned short tile[9 * 4 * 130 * 8];  // 74,880 B
  __shared__ float sBias[64];
  const int tid = threadIdx.x;
  const int bl = blockIdx.y;
  const int r = __builtin_amdgcn_readfirstlane(rgn[b0 + bl]);
  if (tid < 64) sBias[tid] = bias[r * 64 + tid];
  const int oy0 = blockIdx.x * 4;
  const int wv = tid >> 6;
  const unsigned short* gsrc =
      in + (size_t)bl * 130 * 130 * 32 + (size_t)(2 * oy0) * 130 * 32;
  // stage 4680 16B chunks: slot c -> (row = c/520, c8 = (c%520)/130, x = c%130)
  for (int seg = 0; seg < 4680; seg += 256) {
    int c = seg + tid;
    if (c < 4680) {
      int row = c / 520;
      int rem = c - row * 520;
      int c8 = rem / 130;
      int x = rem - c8 * 130;
      const unsigned short* gp = gsrc + (size_t)(row * 130 + x) * 32 + c8 * 8;
      g2l16(gp, tile + (size_t)(seg + wv * 64) * 8);
    }
  }
  __syncthreads();
  const int n = tid & 15, q = (tid >> 4) & 3, w = tid >> 6;
  const short8* wpb = (const short8*)wp + (size_t)r * 9 * 4 * 64 + (tid & 63);
  floatx4 acc[4][4];
#pragma unroll
  for (int nt = 0; nt < 4; ++nt)
#pragma unroll
    for (int m = 0; m < 4; ++m) acc[nt][m] = (floatx4){0.f, 0.f, 0.f, 0.f};
#pragma unroll
  for (int tap = 0; tap < 9; ++tap) {
    const int ky = tap / 3, kx = tap % 3;
    short8 afr[4];
#pragma unroll
    for (int m = 0; m < 4; ++m) afr[m] = wpb[(tap * 4 + m) * 64];
    short8 bfr[4];
#pragma unroll
    for (int nt = 0; nt < 4; ++nt) {
      int ox = nt * 16 + n;
      bfr[nt] = *(const short8*)&tile[((((2 * w + ky) << 2) + q) * 130 +
                                      (2 * ox + kx)) * 8];
    }
#pragma unroll
    for (int m = 0; m < 4; ++m)
#pragma unroll
      for (int nt = 0; nt < 4; ++nt)
        acc[nt][m] = __builtin_amdgcn_mfma_f32_16x16x32_bf16(afr[m], bfr[nt],
                                                             acc[nt][m], 0, 0, 0);
  }
  unsigned short* ob = outp + (size_t)bl * 66 * 66 * 64;
  const int oy = oy0 + w;
#pragma unroll
  for (int nt = 0; nt < 4; ++nt) {
    int ox = nt * 16 + n;
#pragma unroll
    for (int m = 0; m < 4; ++m) {
      ushort4v st;
#pragma unroll
      for (int rr = 0; rr < 4; ++rr) {
        float v = acc[nt][m][rr] + sBias[m * 16 + q * 4 + rr];
        st[rr] = f2bf(v > 0.f ? v : 0.f);
      }
      *(ushort4v*)(ob + ((size_t)(oy + 1) * 66 + ox + 1) * 64 + m * 16 + q * 4) = st;
    }
  }
}

// conv3: 64->128, 32x32 out, fused bias+ReLU+GAP. Block = 128 thr (2 waves),
// 4 out rows x 32 px; wave wv covers local rows 2wv..2wv+1. All 128 oc
// (acc[4][8] = 128 AGPR). Two 32-ch K-phases; tile [iy 0..8][c8][x][8] =
// 38,016 B staged via global_load_lds. GAP: shfl reduce -> LDS cross-wave
// combine -> one coalesced atomicAdd per oc.
__global__ __launch_bounds__(128, 2) void conv3lds_k(
    const unsigned short* __restrict__ in, const unsigned short* __restrict__ wp,
    const float* __restrict__ bias, const int* __restrict__ rgn,
    float* __restrict__ feat, int b0) {
  __shared__ unsigned short tile[9 * 4 * 66 * 8];  // 38,016 B
  __shared__ float sBias[128];
  __shared__ float sGap[2 * 128];
  const int tid = threadIdx.x;
  const int bl = blockIdx.y;
  const int b = b0 + bl;
  const int r = __builtin_amdgcn_readfirstlane(rgn[b]);
  sBias[tid] = bias[r * 128 + tid];
  const int oy0 = blockIdx.x * 4;
  const unsigned short* gbase =
      in + (size_t)bl * 66 * 66 * 64 + (size_t)(2 * oy0) * 66 * 64;
  const int lane = tid & 63, wv = tid >> 6;
  const int n = lane & 15, q = (lane >> 4) & 3;
  const short8* wpb = (const short8*)wp + (size_t)r * 9 * 2 * 8 * 64 + lane;
  floatx4 acc[4][8];
#pragma unroll
  for (int nt = 0; nt < 4; ++nt)
#pragma unroll
    for (int m = 0; m < 8; ++m) acc[nt][m] = (floatx4){0.f, 0.f, 0.f, 0.f};
#pragma unroll
  for (int s = 0; s < 2; ++s) {
    __syncthreads();  // previous phase's reads done before restage
    // stage 2376 chunks: slot c -> (iy = c/264, c8 = (c%264)/66, x = c%66)
    for (int seg = 0; seg < 2376; seg += 128) {
      int c = seg + tid;
      if (c < 2376) {
        int iy = c / 264;
        int rem = c - iy * 264;
        int c8 = rem / 66;
        int x = rem - c8 * 66;
        const unsigned short* gp =
            gbase + (size_t)(iy * 66 + x) * 64 + s * 32 + c8 * 8;
        g2l16(gp, tile + (size_t)(seg + wv * 64) * 8);
      }
    }
    __syncthreads();
#pragma unroll
    for (int tap = 0; tap < 9; ++tap) {
      const int ky = tap / 3, kx = tap % 3;
      short8 afr[8];
#pragma unroll
      for (int m = 0; m < 8; ++m) afr[m] = wpb[((tap * 2 + s) * 8 + m) * 64];
      short8 bfr[4];
#pragma unroll
      for (int nt = 0; nt < 4; ++nt) {
        int oyl = 2 * wv + (nt >> 1);          // local out row 0..3
        int ox = ((nt & 1) << 4) + n;          // 0..31
        bfr[nt] = *(const short8*)&tile[(((2 * oyl + ky) * 4 + q) * 66 +
                                        (2 * ox + kx)) * 8];
      }
#pragma unroll
      for (int m = 0; m < 8; ++m)
#pragma unroll
        for (int nt = 0; nt < 4; ++nt)
          acc[nt][m] = __builtin_amdgcn_mfma_f32_16x16x32_bf16(afr[m], bfr[nt],
                                                               acc[nt][m], 0, 0, 0);
    }
  }
  // bias + ReLU + GAP: per-wave shfl reduce, LDS cross-wave combine
#pragma unroll
  for (int m = 0; m < 8; ++m)
#pragma unroll
    for (int rr = 0; rr < 4; ++rr) {
      float bv = sBias[m * 16 + q * 4 + rr];
      float vs = 0.f;
#pragma unroll
      for (int nt = 0; nt < 4; ++nt) {
        float v = acc[nt][m][rr] + bv;
        vs += (v > 0.f ? v : 0.f);
      }
      vs += __shfl_xor(vs, 1, 16);
      vs += __shfl_xor(vs, 2, 16);
      vs += __shfl_xor(vs, 4, 16);
      vs += __shfl_xor(vs, 8, 16);
      if (n == 0) sGap[wv * 128 + m * 16 + q * 4 + rr] = vs;
    }
  __syncthreads();
  atomicAdd(&feat[b * 128 + tid], sGap[tid] + sGap[128 + tid]);
}

__global__ __launch_bounds__(256) void head_k(
    const float* __restrict__ feat, const float* __restrict__ fw,
    const float* __restrict__ fb, const int* __restrict__ rgn,
    float* __restrict__ out) {
  int t = threadIdx.x;  // 128 samples x 2 classes
  int b = t >> 1, c = t & 1;
  int r = rgn[b];
  const float* fwr = fw + (r * 2 + c) * 128;
  const float* fv = feat + b * 128;
  float a = 0.f;
#pragma unroll 8
  for (int j = 0; j < 128; ++j) a = fmaf(fwr[j], fv[j], a);
  out[t] = a * (1.0f / 1024.0f) + fb[r * 2 + c];
}

extern "C" void kernel_launch(void* const* d_in, const int* in_sizes, int n_in,
                              void* d_out, int out_size, void* d_ws, size_t ws_size,
                              hipStream_t stream) {
  const float* img = (const float*)d_in[0];
  const int* rgn_raw = (const int*)d_in[1];
  const float* w1 = (const float*)d_in[2];
  const float* b1 = (const float*)d_in[3];
  const float* w2 = (const float*)d_in[4];
  const float* b2 = (const float*)d_in[5];
  const float* w3 = (const float*)d_in[6];
  const float* b3 = (const float*)d_in[7];
  const float* fw = (const float*)d_in[8];
  const float* fb = (const float*)d_in[9];
  float* out = (float*)d_out;

  const size_t imgp_s = (size_t)258 * 258 * 4 * 2;   // 532 KB
  const size_t h1p_s = (size_t)130 * 130 * 32 * 2;   // 1.08 MB
  const size_t h2p_s = (size_t)66 * 66 * 64 * 2;     // 557 KB
  const size_t per_sample = imgp_s + h1p_s + h2p_s;  // ~2.17 MB
  const size_t fixed = (size_t)16384 * 2 + (size_t)147456 * 2 +
                       (size_t)589824 * 2 + 128 * 128 * 4 + 512 + 16 * 256;
  int C = 128;
  while (C > 1 && fixed + (size_t)C * per_sample > ws_size) C >>= 1;

  char* ws = (char*)d_ws;
  size_t off = 0;
  auto alloc = [&](size_t bytes) {
    char* p = ws + off;
    off += (bytes + 255) & ~(size_t)255;
    return p;
  };
  unsigned short* imgp = (unsigned short*)alloc((size_t)C * imgp_s);
  unsigned short* h1p = (unsigned short*)alloc((size_t)C * h1p_s);
  unsigned short* h2p = (unsigned short*)alloc((size_t)C * h2p_s);
  unsigned short* w1p = (unsigned short*)alloc((size_t)16384 * 2);
  unsigned short* w2p = (unsigned short*)alloc((size_t)147456 * 2);
  unsigned short* w3p = (unsigned short*)alloc((size_t)589824 * 2);
  float* feat = (float*)alloc((size_t)128 * 128 * 4);
  int* rgn = (int*)alloc((size_t)128 * 4);

  hipLaunchKernelGGL(prep_k, dim3(1), dim3(128), 0, stream, rgn_raw, rgn, feat);
  hipLaunchKernelGGL(pack1_k, dim3(64), dim3(256), 0, stream, w1, w1p);
  hipLaunchKernelGGL((packT_k<64, 32, 1, 4>), dim3(576), dim3(256), 0, stream, w2, w2p);
  hipLaunchKernelGGL((packT_k<128, 64, 2, 8>), dim3(2304), dim3(256), 0, stream, w3, w3p);
  {  // zero halos once; interiors rewritten every chunk
    int n0 = C * (2 * 258 + 2 * 256);
    hipLaunchKernelGGL(halo4_k, dim3((n0 + 255) / 256), dim3(256), 0, stream, imgp, C);
    int n1 = C * (2 * 130 + 2 * 128);
    hipLaunchKernelGGL((haloc_k<32>), dim3((n1 + 255) / 256), dim3(256), 0, stream,
                       h1p, C, 130, 130);
    int n2 = C * (2 * 66 + 2 * 64);
    hipLaunchKernelGGL((haloc_k<64>), dim3((n2 + 255) / 256), dim3(256), 0, stream,
                       h2p, C, 66, 66);
  }

  for (int b0 = 0; b0 < 128; b0 += C) {
    hipLaunchKernelGGL(imgcvt_k, dim3(64, C), dim3(256), 0, stream, img, imgp, b0);
    hipLaunchKernelGGL(conv1_k, dim3(64, C), dim3(256), 0, stream,
                       imgp, w1p, b1, rgn, h1p, b0);
    // conv2: 16 row-group blocks (4 rows x 64 px each) per sample
    hipLaunchKernelGGL(conv2lds_k, dim3(16, C), dim3(256), 0, stream,
                       h1p, w2p, b2, rgn, h2p, b0);
    // conv3: 8 row-group blocks (4 rows x 32 px each) per sample, 128 thr
    hipLaunchKernelGGL(conv3lds_k, dim3(8, C), dim3(128), 0, stream,
                       h2p, w3p, b3, rgn, feat, b0);
  }
  hipLaunchKernelGGL(head_k, dim3(1), dim3(256), 0, stream, feat, fw, fb, rgn, out);
}

// Round 12
// 357.846 us; speedup vs baseline: 1.0375x; 1.0375x over previous
//
#include <hip/hip_runtime.h>
#include <cstdint>

// ---------------------------------------------------------------------------
// RegionModel R12: channel-group-blocked activation layout [c8][y][x][8ch].
// R11's global_load_lds staging read 16B chunks at 128B stride (transpose
// folded into GLOBAL addresses) -> ~30% HBM efficiency, conv3 62us vs 20us
// floor. R12 moves the transpose to the PRODUCER: h1/h2 stored [c8][y][x][8],
// so staging chunk c=[row][c8][x] is contiguous in x -> coalesced 1KB per
// wave DMA. LDS layout & MFMA K-loops byte-identical to R11 (which passed).
// conv1/conv2 stores now 8B @ 16B stride. Halos zeroed per [c8] plane.
// ---------------------------------------------------------------------------

typedef __attribute__((ext_vector_type(8))) short short8;
typedef __attribute__((ext_vector_type(4))) float floatx4;
typedef __attribute__((ext_vector_type(4))) unsigned short ushort4v;
typedef __attribute__((ext_vector_type(4))) float float4v;

__device__ inline unsigned short f2bf(float f) {
  union { float f; unsigned u; } x;
  x.f = f;
  unsigned u = x.u;
  u += 0x7FFFu + ((u >> 16) & 1u);  // round-to-nearest-even
  return (unsigned short)(u >> 16);
}

// Async 16B global->LDS DMA. LDS dest = wave-uniform base + lane*16.
__device__ inline void g2l16(const unsigned short* g, unsigned short* l) {
  __builtin_amdgcn_global_load_lds(
      (const __attribute__((address_space(1))) unsigned int*)g,
      (__attribute__((address_space(3))) unsigned int*)(unsigned int)(uintptr_t)l,
      16, 0, 0);
}

__global__ __launch_bounds__(128) void prep_k(const int* __restrict__ rp,
                                              int* __restrict__ rout,
                                              float* __restrict__ feat) {
  __shared__ int is64;
  if (threadIdx.x == 0) {
    int odd_or = 0;
    for (int i = 0; i < 64; ++i) odd_or |= rp[2 * i + 1];
    is64 = (odd_or == 0) ? 1 : 0;
  }
  __syncthreads();
  int b = threadIdx.x;
  int r = is64 ? rp[2 * b] : rp[b];
  rout[b] = r & 7;
  float* fr = feat + b * 128;
  for (int j = 0; j < 128; ++j) fr[j] = 0.f;
}

// conv1 weights -> [r][kg(2)][mt(2)][lane][j] ; k = kg*32+q*8+j maps to
// row = kg*2+(q>>1), idx=(q&1)*8+j, kx=idx>>2, c=idx&3; pad slots -> 0.
__global__ __launch_bounds__(256) void pack1_k(const float* __restrict__ w,
                                               unsigned short* __restrict__ dst) {
  int t = blockIdx.x * blockDim.x + threadIdx.x;
  if (t >= 16384) return;
  int j = t & 7, lane = (t >> 3) & 63, mt = (t >> 9) & 1, kg = (t >> 10) & 1,
      r = t >> 11;
  int oc = mt * 16 + (lane & 15);
  int q = (lane >> 4) & 3;
  int row = kg * 2 + (q >> 1);
  int idx = (q & 1) * 8 + j;
  int kx = idx >> 2, c = idx & 3;
  float val = 0.f;
  if (row < 3 && kx < 3 && c < 3) val = w[((r * 32 + oc) * 3 + c) * 9 + row * 3 + kx];
  dst[t] = f2bf(val);
}

// conv2/3 weights [R][OC][IC][3][3] -> [r][tap][s][mt][lane][j], ic=s*32+q*8+j
template <int OC, int IC, int SUBK, int MTG>
__global__ __launch_bounds__(256) void packT_k(const float* __restrict__ w,
                                               unsigned short* __restrict__ dst) {
  const int total = 8 * 9 * SUBK * MTG * 512;
  int t = blockIdx.x * blockDim.x + threadIdx.x;
  if (t >= total) return;
  int j = t & 7, lane = (t >> 3) & 63;
  int u = t >> 9;
  int mt = u % MTG; u /= MTG;
  int s = u % SUBK; u /= SUBK;
  int tap = u % 9;
  int r = u / 9;
  int oc = mt * 16 + (lane & 15);
  int ic = s * 32 + ((lane >> 4) & 3) * 8 + j;
  dst[t] = f2bf(w[((r * OC + oc) * IC + ic) * 9 + tap]);
}

// fp32 planar image -> padded c-last bf16 interior [s][258][258][4].
__global__ __launch_bounds__(256) void imgcvt_k(const float* __restrict__ img,
                                                unsigned short* __restrict__ dst,
                                                int b0) {
  int idx = blockIdx.x * 256 + threadIdx.x;  // 0..16383 per sample
  int y = idx >> 6, xq = idx & 63;
  int s = blockIdx.y;
  const float* ip = img + ((size_t)(b0 + s) * 3) * 65536 + y * 256 + xq * 4;
  float4v a = *(const float4v*)ip;
  float4v bb = *(const float4v*)(ip + 65536);
  float4v cc = *(const float4v*)(ip + 131072);
  unsigned short* dp =
      dst + ((size_t)s * 258 * 258 + (size_t)(y + 1) * 258 + xq * 4 + 1) * 4;
#pragma unroll
  for (int i = 0; i < 4; ++i) {
    ushort4v v = {f2bf(a[i]), f2bf(bb[i]), f2bf(cc[i]), 0};
    *(ushort4v*)(dp + i * 4) = v;
  }
}

// zero halo of padded image buffer [nsamp][258][258][4]
__global__ __launch_bounds__(256) void halo4_k(unsigned short* __restrict__ buf,
                                               int nsamp) {
  const int per = 2 * 258 + 2 * 256;
  int t = blockIdx.x * blockDim.x + threadIdx.x;
  if (t >= nsamp * per) return;
  int s = t / per, i = t - s * per;
  int y, x;
  if (i < 258) { y = 0; x = i; }
  else if (i < 516) { y = 257; x = i - 258; }
  else {
    int ii = i - 516;
    y = 1 + (ii >> 1);
    x = (ii & 1) ? 257 : 0;
  }
  ushort4v z = {0, 0, 0, 0};
  *(ushort4v*)(buf + ((size_t)s * 258 * 258 + y * 258 + x) * 4) = z;
}

// zero halo of channel-group plane buffer [nplane][HP][WP][8]
__global__ __launch_bounds__(256) void halo8_k(unsigned short* __restrict__ buf,
                                               int nplane, int HP, int WP) {
  int per = 2 * WP + 2 * (HP - 2);
  int t = blockIdx.x * blockDim.x + threadIdx.x;
  if (t >= nplane * per) return;
  int s = t / per, i = t - s * per;
  int y, x;
  if (i < WP) { y = 0; x = i; }
  else if (i < 2 * WP) { y = HP - 1; x = i - WP; }
  else {
    int ii = i - 2 * WP;
    y = 1 + (ii >> 1);
    x = (ii & 1) ? (WP - 1) : 0;
  }
  short8 z = {0, 0, 0, 0, 0, 0, 0, 0};
  *(short8*)(buf + ((size_t)s * HP * WP + y * WP + x) * 8) = z;
}

// conv1: 3->32, 256->128. imgp [258][258][4] c-last, K = 3 rows x 16.
// Output h1p layout [c8=4][130][130][8].
__global__ __launch_bounds__(256, 4) void conv1_k(
    const unsigned short* __restrict__ in, const unsigned short* __restrict__ wp,
    const float* __restrict__ bias, const int* __restrict__ rgn,
    unsigned short* __restrict__ outp, int b0) {
  const int tid = threadIdx.x;
  const int bl = blockIdx.y;
  const int r = __builtin_amdgcn_readfirstlane(rgn[b0 + bl]);
  __shared__ float sBias[32];
  if (tid < 32) sBias[tid] = bias[r * 32 + tid];
  __syncthreads();
  const int n = tid & 15, q = (tid >> 4) & 3;
  const int lane = tid & 63;
  const int px0 = (blockIdx.x * 4 + (tid >> 6)) * 64;
  const unsigned short* inb = in + (size_t)bl * 258 * 258 * 4 + (q & 1) * 8;
  int oyA[4], oxA[4];
  const unsigned short* pB[4];
#pragma unroll
  for (int nt = 0; nt < 4; ++nt) {
    int px = px0 + nt * 16 + n;
    oyA[nt] = px >> 7;
    oxA[nt] = px & 127;
    pB[nt] = inb + ((size_t)(2 * oyA[nt]) * 258 + 2 * oxA[nt]) * 4;
  }
  const short8* wpb = (const short8*)wp + (size_t)r * 256 + lane;
  short8 bfr[2][4];
#pragma unroll
  for (int kg = 0; kg < 2; ++kg) {
    int row = kg * 2 + (q >> 1);
    int rowc = (row < 3) ? row : 0;  // pad rows: zero weights, safe addr
#pragma unroll
    for (int nt = 0; nt < 4; ++nt)
      bfr[kg][nt] = *(const short8*)(pB[nt] + (size_t)rowc * 258 * 4);
  }
  short8 afr[2][2];
#pragma unroll
  for (int kg = 0; kg < 2; ++kg)
#pragma unroll
    for (int m = 0; m < 2; ++m) afr[kg][m] = wpb[(kg * 2 + m) * 64];
  floatx4 acc[4][2];
#pragma unroll
  for (int nt = 0; nt < 4; ++nt)
#pragma unroll
    for (int m = 0; m < 2; ++m) acc[nt][m] = (floatx4){0.f, 0.f, 0.f, 0.f};
#pragma unroll
  for (int kg = 0; kg < 2; ++kg)
#pragma unroll
    for (int m = 0; m < 2; ++m)
#pragma unroll
      for (int nt = 0; nt < 4; ++nt)
        acc[nt][m] = __builtin_amdgcn_mfma_f32_16x16x32_bf16(afr[kg][m], bfr[kg][nt],
                                                             acc[nt][m], 0, 0, 0);
  unsigned short* ob = outp + (size_t)bl * 4 * 130 * 130 * 8;
#pragma unroll
  for (int nt = 0; nt < 4; ++nt)
#pragma unroll
    for (int m = 0; m < 2; ++m) {
      ushort4v st;
#pragma unroll
      for (int rr = 0; rr < 4; ++rr) {
        float v = acc[nt][m][rr] + sBias[m * 16 + q * 4 + rr];
        st[rr] = f2bf(v > 0.f ? v : 0.f);
      }
      int cg = m * 2 + (q >> 1);  // oc/8
      *(ushort4v*)(ob + (((size_t)cg * 130 + oyA[nt] + 1) * 130 + oxA[nt] + 1) * 8 +
                   (q & 1) * 4) = st;
    }
}

// conv2: 32->64, 64x64 out. Block = 4 out rows x 64 px. h1p [c8=4][130][130][8].
// LDS tile [row][c8][x][8] = chunk c*16B; global chunk run contiguous in x.
__global__ __launch_bounds__(256, 2) void conv2lds_k(
    const unsigned short* __restrict__ in, const unsigned short* __restrict__ wp,
    const float* __restrict__ bias, const int* __restrict__ rgn,
    unsigned short* __restrict__ outp, int b0) {
  __shared__ unsigned short tile[9 * 4 * 130 * 8];  // 74,880 B
  __shared__ float sBias[64];
  const int tid = threadIdx.x;
  const int bl = blockIdx.y;
  const int r = __builtin_amdgcn_readfirstlane(rgn[b0 + bl]);
  if (tid < 64) sBias[tid] = bias[r * 64 + tid];
  const int oy0 = blockIdx.x * 4;
  const int wv = tid >> 6;
  const unsigned short* gsrc = in + (size_t)bl * 4 * 130 * 130 * 8;
  // stage 4680 chunks: c -> (row=c/520, c8=(c%520)/130, x=c%130);
  // global = ((c8*130 + 2*oy0+row)*130 + x)*8 -- contiguous in x.
  for (int seg = 0; seg < 4680; seg += 256) {
    int c = seg + tid;
    if (c < 4680) {
      int row = c / 520;
      int rem = c - row * 520;
      int c8 = rem / 130;
      int x = rem - c8 * 130;
      const unsigned short* gp =
          gsrc + (((size_t)c8 * 130 + 2 * oy0 + row) * 130 + x) * 8;
      g2l16(gp, tile + (size_t)(seg + wv * 64) * 8);
    }
  }
  __syncthreads();
  const int n = tid & 15, q = (tid >> 4) & 3, w = tid >> 6;
  const short8* wpb = (const short8*)wp + (size_t)r * 9 * 4 * 64 + (tid & 63);
  floatx4 acc[4][4];
#pragma unroll
  for (int nt = 0; nt < 4; ++nt)
#pragma unroll
    for (int m = 0; m < 4; ++m) acc[nt][m] = (floatx4){0.f, 0.f, 0.f, 0.f};
#pragma unroll
  for (int tap = 0; tap < 9; ++tap) {
    const int ky = tap / 3, kx = tap % 3;
    short8 afr[4];
#pragma unroll
    for (int m = 0; m < 4; ++m) afr[m] = wpb[(tap * 4 + m) * 64];
    short8 bfr[4];
#pragma unroll
    for (int nt = 0; nt < 4; ++nt) {
      int ox = nt * 16 + n;
      bfr[nt] = *(const short8*)&tile[((((2 * w + ky) << 2) + q) * 130 +
                                      (2 * ox + kx)) * 8];
    }
#pragma unroll
    for (int m = 0; m < 4; ++m)
#pragma unroll
      for (int nt = 0; nt < 4; ++nt)
        acc[nt][m] = __builtin_amdgcn_mfma_f32_16x16x32_bf16(afr[m], bfr[nt],
                                                             acc[nt][m], 0, 0, 0);
  }
  unsigned short* ob = outp + (size_t)bl * 8 * 66 * 66 * 8;
  const int oy = oy0 + w;
#pragma unroll
  for (int nt = 0; nt < 4; ++nt) {
    int ox = nt * 16 + n;
#pragma unroll
    for (int m = 0; m < 4; ++m) {
      ushort4v st;
#pragma unroll
      for (int rr = 0; rr < 4; ++rr) {
        float v = acc[nt][m][rr] + sBias[m * 16 + q * 4 + rr];
        st[rr] = f2bf(v > 0.f ? v : 0.f);
      }
      int cg = m * 2 + (q >> 1);  // oc/8
      *(ushort4v*)(ob + (((size_t)cg * 66 + oy + 1) * 66 + ox + 1) * 8 +
                   (q & 1) * 4) = st;
    }
  }
}

// conv3: 64->128, 32x32 out, fused bias+ReLU+GAP. h2p [c8=8][66][66][8].
// Block = 128 thr (2 waves), 4 out rows x 32 px, all 128 oc (acc 128 AGPR).
// Two 32-ch K-phases; tile [iy][c8][x][8] = 38,016 B; chunks contiguous in x.
__global__ __launch_bounds__(128, 2) void conv3lds_k(
    const unsigned short* __restrict__ in, const unsigned short* __restrict__ wp,
    const float* __restrict__ bias, const int* __restrict__ rgn,
    float* __restrict__ feat, int b0) {
  __shared__ unsigned short tile[9 * 4 * 66 * 8];  // 38,016 B
  __shared__ float sBias[128];
  __shared__ float sGap[2 * 128];
  const int tid = threadIdx.x;
  const int bl = blockIdx.y;
  const int b = b0 + bl;
  const int r = __builtin_amdgcn_readfirstlane(rgn[b]);
  sBias[tid] = bias[r * 128 + tid];
  const int oy0 = blockIdx.x * 4;
  const unsigned short* gbase = in + (size_t)bl * 8 * 66 * 66 * 8;
  const int lane = tid & 63, wv = tid >> 6;
  const int n = lane & 15, q = (lane >> 4) & 3;
  const short8* wpb = (const short8*)wp + (size_t)r * 9 * 2 * 8 * 64 + lane;
  floatx4 acc[4][8];
#pragma unroll
  for (int nt = 0; nt < 4; ++nt)
#pragma unroll
    for (int m = 0; m < 8; ++m) acc[nt][m] = (floatx4){0.f, 0.f, 0.f, 0.f};
#pragma unroll
  for (int s = 0; s < 2; ++s) {
    __syncthreads();  // previous phase's reads done before restage
    // 2376 chunks: c -> (iy=c/264, c8=(c%264)/66, x=c%66);
    // global = (((s*4+c8)*66 + 2*oy0+iy)*66 + x)*8 -- contiguous in x.
    for (int seg = 0; seg < 2376; seg += 128) {
      int c = seg + tid;
      if (c < 2376) {
        int iy = c / 264;
        int rem = c - iy * 264;
        int c8 = rem / 66;
        int x = rem - c8 * 66;
        const unsigned short* gp =
            gbase + (((size_t)(s * 4 + c8) * 66 + 2 * oy0 + iy) * 66 + x) * 8;
        g2l16(gp, tile + (size_t)(seg + wv * 64) * 8);
      }
    }
    __syncthreads();
#pragma unroll
    for (int tap = 0; tap < 9; ++tap) {
      const int ky = tap / 3, kx = tap % 3;
      short8 afr[8];
#pragma unroll
      for (int m = 0; m < 8; ++m) afr[m] = wpb[((tap * 2 + s) * 8 + m) * 64];
      short8 bfr[4];
#pragma unroll
      for (int nt = 0; nt < 4; ++nt) {
        int oyl = 2 * wv + (nt >> 1);          // local out row 0..3
        int ox = ((nt & 1) << 4) + n;          // 0..31
        bfr[nt] = *(const short8*)&tile[(((2 * oyl + ky) * 4 + q) * 66 +
                                        (2 * ox + kx)) * 8];
      }
#pragma unroll
      for (int m = 0; m < 8; ++m)
#pragma unroll
        for (int nt = 0; nt < 4; ++nt)
          acc[nt][m] = __builtin_amdgcn_mfma_f32_16x16x32_bf16(afr[m], bfr[nt],
                                                               acc[nt][m], 0, 0, 0);
    }
  }
  // bias + ReLU + GAP: per-wave shfl reduce, LDS cross-wave combine
#pragma unroll
  for (int m = 0; m < 8; ++m)
#pragma unroll
    for (int rr = 0; rr < 4; ++rr) {
      float bv = sBias[m * 16 + q * 4 + rr];
      float vs = 0.f;
#pragma unroll
      for (int nt = 0; nt < 4; ++nt) {
        float v = acc[nt][m][rr] + bv;
        vs += (v > 0.f ? v : 0.f);
      }
      vs += __shfl_xor(vs, 1, 16);
      vs += __shfl_xor(vs, 2, 16);
      vs += __shfl_xor(vs, 4, 16);
      vs += __shfl_xor(vs, 8, 16);
      if (n == 0) sGap[wv * 128 + m * 16 + q * 4 + rr] = vs;
    }
  __syncthreads();
  atomicAdd(&feat[b * 128 + tid], sGap[tid] + sGap[128 + tid]);
}

__global__ __launch_bounds__(256) void head_k(
    const float* __restrict__ feat, const float* __restrict__ fw,
    const float* __restrict__ fb, const int* __restrict__ rgn,
    float* __restrict__ out) {
  int t = threadIdx.x;  // 128 samples x 2 classes
  int b = t >> 1, c = t & 1;
  int r = rgn[b];
  const float* fwr = fw + (r * 2 + c) * 128;
  const float* fv = feat + b * 128;
  float a = 0.f;
#pragma unroll 8
  for (int j = 0; j < 128; ++j) a = fmaf(fwr[j], fv[j], a);
  out[t] = a * (1.0f / 1024.0f) + fb[r * 2 + c];
}

extern "C" void kernel_launch(void* const* d_in, const int* in_sizes, int n_in,
                              void* d_out, int out_size, void* d_ws, size_t ws_size,
                              hipStream_t stream) {
  const float* img = (const float*)d_in[0];
  const int* rgn_raw = (const int*)d_in[1];
  const float* w1 = (const float*)d_in[2];
  const float* b1 = (const float*)d_in[3];
  const float* w2 = (const float*)d_in[4];
  const float* b2 = (const float*)d_in[5];
  const float* w3 = (const float*)d_in[6];
  const float* b3 = (const float*)d_in[7];
  const float* fw = (const float*)d_in[8];
  const float* fb = (const float*)d_in[9];
  float* out = (float*)d_out;

  const size_t imgp_s = (size_t)258 * 258 * 4 * 2;   // 532 KB
  const size_t h1p_s = (size_t)4 * 130 * 130 * 8 * 2;  // 1.08 MB
  const size_t h2p_s = (size_t)8 * 66 * 66 * 8 * 2;    // 557 KB
  const size_t per_sample = imgp_s + h1p_s + h2p_s;  // ~2.17 MB
  const size_t fixed = (size_t)16384 * 2 + (size_t)147456 * 2 +
                       (size_t)589824 * 2 + 128 * 128 * 4 + 512 + 16 * 256;
  int C = 128;
  while (C > 1 && fixed + (size_t)C * per_sample > ws_size) C >>= 1;

  char* ws = (char*)d_ws;
  size_t off = 0;
  auto alloc = [&](size_t bytes) {
    char* p = ws + off;
    off += (bytes + 255) & ~(size_t)255;
    return p;
  };
  unsigned short* imgp = (unsigned short*)alloc((size_t)C * imgp_s);
  unsigned short* h1p = (unsigned short*)alloc((size_t)C * h1p_s);
  unsigned short* h2p = (unsigned short*)alloc((size_t)C * h2p_s);
  unsigned short* w1p = (unsigned short*)alloc((size_t)16384 * 2);
  unsigned short* w2p = (unsigned short*)alloc((size_t)147456 * 2);
  unsigned short* w3p = (unsigned short*)alloc((size_t)589824 * 2);
  float* feat = (float*)alloc((size_t)128 * 128 * 4);
  int* rgn = (int*)alloc((size_t)128 * 4);

  hipLaunchKernelGGL(prep_k, dim3(1), dim3(128), 0, stream, rgn_raw, rgn, feat);
  hipLaunchKernelGGL(pack1_k, dim3(64), dim3(256), 0, stream, w1, w1p);
  hipLaunchKernelGGL((packT_k<64, 32, 1, 4>), dim3(576), dim3(256), 0, stream, w2, w2p);
  hipLaunchKernelGGL((packT_k<128, 64, 2, 8>), dim3(2304), dim3(256), 0, stream, w3, w3p);
  {  // zero halos once; interiors rewritten every chunk
    int n0 = C * (2 * 258 + 2 * 256);
    hipLaunchKernelGGL(halo4_k, dim3((n0 + 255) / 256), dim3(256), 0, stream, imgp, C);
    int n1 = C * 4 * (2 * 130 + 2 * 128);
    hipLaunchKernelGGL(halo8_k, dim3((n1 + 255) / 256), dim3(256), 0, stream,
                       h1p, C * 4, 130, 130);
    int n2 = C * 8 * (2 * 66 + 2 * 64);
    hipLaunchKernelGGL(halo8_k, dim3((n2 + 255) / 256), dim3(256), 0, stream,
                       h2p, C * 8, 66, 66);
  }

  for (int b0 = 0; b0 < 128; b0 += C) {
    hipLaunchKernelGGL(imgcvt_k, dim3(64, C), dim3(256), 0, stream, img, imgp, b0);
    hipLaunchKernelGGL(conv1_k, dim3(64, C), dim3(256), 0, stream,
                       imgp, w1p, b1, rgn, h1p, b0);
    // conv2: 16 row-group blocks (4 rows x 64 px each) per sample
    hipLaunchKernelGGL(conv2lds_k, dim3(16, C), dim3(256), 0, stream,
                       h1p, w2p, b2, rgn, h2p, b0);
    // conv3: 8 row-group blocks (4 rows x 32 px each) per sample, 128 thr
    hipLaunchKernelGGL(conv3lds_k, dim3(8, C), dim3(128), 0, stream,
                       h2p, w3p, b3, rgn, feat, b0);
  }
  hipLaunchKernelGGL(head_k, dim3(1), dim3(256), 0, stream, feat, fw, fb, rgn, out);
}

// Round 13
// 332.466 us; speedup vs baseline: 1.1167x; 1.0763x over previous
//
#include <hip/hip_runtime.h>
#include <cstdint>

// ---------------------------------------------------------------------------
// RegionModel R13: fuse imgcvt INTO conv1 (LDS-staged fp32->bf16).
// R12 left imgcvt_k as the top real kernel (60.6us, 2.2x its 27us floor,
// latency-bound) producing a 68MB intermediate conv1 re-reads. R13: conv1
// stages its 9x258 fp32 rows x3 planes straight from img into an LDS tile
// [9][258][4ch] bf16 (18.6KB, halo zeroed by predicate), MFMA from LDS.
// Deletes imgcvt dispatch + imgp buffer + halo4 + ~90MB of HBM round-trip.
// conv2/conv3 unchanged from R12 (channel-group-blocked [c8][y][x][8],
// coalesced global_load_lds staging - R12 dropped them out of top-5).
// ---------------------------------------------------------------------------

typedef __attribute__((ext_vector_type(8))) short short8;
typedef __attribute__((ext_vector_type(4))) float floatx4;
typedef __attribute__((ext_vector_type(4))) unsigned short ushort4v;
typedef __attribute__((ext_vector_type(4))) float float4v;

__device__ inline unsigned short f2bf(float f) {
  union { float f; unsigned u; } x;
  x.f = f;
  unsigned u = x.u;
  u += 0x7FFFu + ((u >> 16) & 1u);  // round-to-nearest-even
  return (unsigned short)(u >> 16);
}

// Async 16B global->LDS DMA. LDS dest = wave-uniform base + lane*16.
__device__ inline void g2l16(const unsigned short* g, unsigned short* l) {
  __builtin_amdgcn_global_load_lds(
      (const __attribute__((address_space(1))) unsigned int*)g,
      (__attribute__((address_space(3))) unsigned int*)(unsigned int)(uintptr_t)l,
      16, 0, 0);
}

__global__ __launch_bounds__(128) void prep_k(const int* __restrict__ rp,
                                              int* __restrict__ rout,
                                              float* __restrict__ feat) {
  __shared__ int is64;
  if (threadIdx.x == 0) {
    int odd_or = 0;
    for (int i = 0; i < 64; ++i) odd_or |= rp[2 * i + 1];
    is64 = (odd_or == 0) ? 1 : 0;
  }
  __syncthreads();
  int b = threadIdx.x;
  int r = is64 ? rp[2 * b] : rp[b];
  rout[b] = r & 7;
  float* fr = feat + b * 128;
  for (int j = 0; j < 128; ++j) fr[j] = 0.f;
}

// conv1 weights -> [r][kg(2)][mt(2)][lane][j] ; k = kg*32+q*8+j maps to
// row = kg*2+(q>>1), idx=(q&1)*8+j, kx=idx>>2, c=idx&3; pad slots -> 0.
__global__ __launch_bounds__(256) void pack1_k(const float* __restrict__ w,
                                               unsigned short* __restrict__ dst) {
  int t = blockIdx.x * blockDim.x + threadIdx.x;
  if (t >= 16384) return;
  int j = t & 7, lane = (t >> 3) & 63, mt = (t >> 9) & 1, kg = (t >> 10) & 1,
      r = t >> 11;
  int oc = mt * 16 + (lane & 15);
  int q = (lane >> 4) & 3;
  int row = kg * 2 + (q >> 1);
  int idx = (q & 1) * 8 + j;
  int kx = idx >> 2, c = idx & 3;
  float val = 0.f;
  if (row < 3 && kx < 3 && c < 3) val = w[((r * 32 + oc) * 3 + c) * 9 + row * 3 + kx];
  dst[t] = f2bf(val);
}

// conv2/3 weights [R][OC][IC][3][3] -> [r][tap][s][mt][lane][j], ic=s*32+q*8+j
template <int OC, int IC, int SUBK, int MTG>
__global__ __launch_bounds__(256) void packT_k(const float* __restrict__ w,
                                               unsigned short* __restrict__ dst) {
  const int total = 8 * 9 * SUBK * MTG * 512;
  int t = blockIdx.x * blockDim.x + threadIdx.x;
  if (t >= total) return;
  int j = t & 7, lane = (t >> 3) & 63;
  int u = t >> 9;
  int mt = u % MTG; u /= MTG;
  int s = u % SUBK; u /= SUBK;
  int tap = u % 9;
  int r = u / 9;
  int oc = mt * 16 + (lane & 15);
  int ic = s * 32 + ((lane >> 4) & 3) * 8 + j;
  dst[t] = f2bf(w[((r * OC + oc) * IC + ic) * 9 + tap]);
}

// zero halo of channel-group plane buffer [nplane][HP][WP][8]
__global__ __launch_bounds__(256) void halo8_k(unsigned short* __restrict__ buf,
                                               int nplane, int HP, int WP) {
  int per = 2 * WP + 2 * (HP - 2);
  int t = blockIdx.x * blockDim.x + threadIdx.x;
  if (t >= nplane * per) return;
  int s = t / per, i = t - s * per;
  int y, x;
  if (i < WP) { y = 0; x = i; }
  else if (i < 2 * WP) { y = HP - 1; x = i - WP; }
  else {
    int ii = i - 2 * WP;
    y = 1 + (ii >> 1);
    x = (ii & 1) ? (WP - 1) : 0;
  }
  short8 z = {0, 0, 0, 0, 0, 0, 0, 0};
  *(short8*)(buf + ((size_t)s * HP * WP + y * WP + x) * 8) = z;
}

// conv1 FUSED: fp32 planar img -> bf16 LDS tile [9][258][4] -> MFMA.
// Block = 4 out rows x 128 px (full row per wave, 8 n-tiles).
// Output h1p layout [c8=4][130][130][8].
__global__ __launch_bounds__(256, 4) void conv1f_k(
    const float* __restrict__ img, const unsigned short* __restrict__ wp,
    const float* __restrict__ bias, const int* __restrict__ rgn,
    unsigned short* __restrict__ outp, int b0) {
  __shared__ unsigned short tile[9 * 258 * 4];  // 18,576 B
  __shared__ float sBias[32];
  const int tid = threadIdx.x;
  const int bl = blockIdx.y;
  const int r = __builtin_amdgcn_readfirstlane(rgn[b0 + bl]);
  if (tid < 32) sBias[tid] = bias[r * 32 + tid];
  const int oy0 = blockIdx.x * 4;
  const float* ib = img + (size_t)(b0 + bl) * 3 * 65536;
  // stage: tile row tr <-> padded row 2*oy0+tr <-> unpadded ur = 2*oy0+tr-1
  for (int seg = 0; seg < 2322; seg += 256) {
    int c = seg + tid;
    if (c < 2322) {
      int tr = c / 258;
      int x = c - tr * 258;
      int ur = 2 * oy0 + tr - 1;
      int uc = x - 1;
      ushort4v v = {0, 0, 0, 0};
      if ((unsigned)ur < 256u && (unsigned)uc < 256u) {
        const float* p = ib + ur * 256 + uc;
        v.x = f2bf(p[0]);
        v.y = f2bf(p[65536]);
        v.z = f2bf(p[131072]);
      }
      *(ushort4v*)&tile[(size_t)c * 4] = v;
    }
  }
  __syncthreads();
  const int n = tid & 15, q = (tid >> 4) & 3, w = tid >> 6;
  const int lane = tid & 63;
  const short8* wpb = (const short8*)wp + (size_t)r * 256 + lane;
  short8 afr[2][2];
#pragma unroll
  for (int kg = 0; kg < 2; ++kg)
#pragma unroll
    for (int m = 0; m < 2; ++m) afr[kg][m] = wpb[(kg * 2 + m) * 64];
  floatx4 acc[8][2];
#pragma unroll
  for (int nt = 0; nt < 8; ++nt)
#pragma unroll
    for (int m = 0; m < 2; ++m) acc[nt][m] = (floatx4){0.f, 0.f, 0.f, 0.f};
#pragma unroll
  for (int kg = 0; kg < 2; ++kg) {
    int row = kg * 2 + (q >> 1);
    int rowc = (row < 3) ? row : 0;  // pad row: zero weights, safe addr
    int tr = 2 * w + rowc;           // 0..8
#pragma unroll
    for (int nt = 0; nt < 8; ++nt) {
      int ox = nt * 16 + n;  // 0..127
      short8 bfr =
          *(const short8*)&tile[((size_t)tr * 258 + 2 * ox) * 4 + (q & 1) * 8];
#pragma unroll
      for (int m = 0; m < 2; ++m)
        acc[nt][m] =
            __builtin_amdgcn_mfma_f32_16x16x32_bf16(afr[kg][m], bfr, acc[nt][m], 0, 0, 0);
    }
  }
  unsigned short* ob = outp + (size_t)bl * 4 * 130 * 130 * 8;
  const int oy = oy0 + w;
#pragma unroll
  for (int nt = 0; nt < 8; ++nt) {
    int ox = nt * 16 + n;
#pragma unroll
    for (int m = 0; m < 2; ++m) {
      ushort4v st;
#pragma unroll
      for (int rr = 0; rr < 4; ++rr) {
        float v = acc[nt][m][rr] + sBias[m * 16 + q * 4 + rr];
        st[rr] = f2bf(v > 0.f ? v : 0.f);
      }
      int cg = m * 2 + (q >> 1);  // oc/8
      *(ushort4v*)(ob + (((size_t)cg * 130 + oy + 1) * 130 + ox + 1) * 8 +
                   (q & 1) * 4) = st;
    }
  }
}

// conv2: 32->64, 64x64 out. Block = 4 out rows x 64 px. h1p [c8=4][130][130][8].
// LDS tile [row][c8][x][8] = chunk c*16B; global chunk run contiguous in x.
__global__ __launch_bounds__(256, 2) void conv2lds_k(
    const unsigned short* __restrict__ in, const unsigned short* __restrict__ wp,
    const float* __restrict__ bias, const int* __restrict__ rgn,
    unsigned short* __restrict__ outp, int b0) {
  __shared__ unsigned short tile[9 * 4 * 130 * 8];  // 74,880 B
  __shared__ float sBias[64];
  const int tid = threadIdx.x;
  const int bl = blockIdx.y;
  const int r = __builtin_amdgcn_readfirstlane(rgn[b0 + bl]);
  if (tid < 64) sBias[tid] = bias[r * 64 + tid];
  const int oy0 = blockIdx.x * 4;
  const int wv = tid >> 6;
  const unsigned short* gsrc = in + (size_t)bl * 4 * 130 * 130 * 8;
  for (int seg = 0; seg < 4680; seg += 256) {
    int c = seg + tid;
    if (c < 4680) {
      int row = c / 520;
      int rem = c - row * 520;
      int c8 = rem / 130;
      int x = rem - c8 * 130;
      const unsigned short* gp =
          gsrc + (((size_t)c8 * 130 + 2 * oy0 + row) * 130 + x) * 8;
      g2l16(gp, tile + (size_t)(seg + wv * 64) * 8);
    }
  }
  __syncthreads();
  const int n = tid & 15, q = (tid >> 4) & 3, w = tid >> 6;
  const short8* wpb = (const short8*)wp + (size_t)r * 9 * 4 * 64 + (tid & 63);
  floatx4 acc[4][4];
#pragma unroll
  for (int nt = 0; nt < 4; ++nt)
#pragma unroll
    for (int m = 0; m < 4; ++m) acc[nt][m] = (floatx4){0.f, 0.f, 0.f, 0.f};
#pragma unroll
  for (int tap = 0; tap < 9; ++tap) {
    const int ky = tap / 3, kx = tap % 3;
    short8 afr[4];
#pragma unroll
    for (int m = 0; m < 4; ++m) afr[m] = wpb[(tap * 4 + m) * 64];
    short8 bfr[4];
#pragma unroll
    for (int nt = 0; nt < 4; ++nt) {
      int ox = nt * 16 + n;
      bfr[nt] = *(const short8*)&tile[((((2 * w + ky) << 2) + q) * 130 +
                                      (2 * ox + kx)) * 8];
    }
#pragma unroll
    for (int m = 0; m < 4; ++m)
#pragma unroll
      for (int nt = 0; nt < 4; ++nt)
        acc[nt][m] = __builtin_amdgcn_mfma_f32_16x16x32_bf16(afr[m], bfr[nt],
                                                             acc[nt][m], 0, 0, 0);
  }
  unsigned short* ob = outp + (size_t)bl * 8 * 66 * 66 * 8;
  const int oy = oy0 + w;
#pragma unroll
  for (int nt = 0; nt < 4; ++nt) {
    int ox = nt * 16 + n;
#pragma unroll
    for (int m = 0; m < 4; ++m) {
      ushort4v st;
#pragma unroll
      for (int rr = 0; rr < 4; ++rr) {
        float v = acc[nt][m][rr] + sBias[m * 16 + q * 4 + rr];
        st[rr] = f2bf(v > 0.f ? v : 0.f);
      }
      int cg = m * 2 + (q >> 1);  // oc/8
      *(ushort4v*)(ob + (((size_t)cg * 66 + oy + 1) * 66 + ox + 1) * 8 +
                   (q & 1) * 4) = st;
    }
  }
}

// conv3: 64->128, 32x32 out, fused bias+ReLU+GAP. h2p [c8=8][66][66][8].
// Block = 128 thr (2 waves), 4 out rows x 32 px, all 128 oc (acc 128 AGPR).
// Two 32-ch K-phases; tile [iy][c8][x][8] = 38,016 B; chunks contiguous in x.
__global__ __launch_bounds__(128, 2) void conv3lds_k(
    const unsigned short* __restrict__ in, const unsigned short* __restrict__ wp,
    const float* __restrict__ bias, const int* __restrict__ rgn,
    float* __restrict__ feat, int b0) {
  __shared__ unsigned short tile[9 * 4 * 66 * 8];  // 38,016 B
  __shared__ float sBias[128];
  __shared__ float sGap[2 * 128];
  const int tid = threadIdx.x;
  const int bl = blockIdx.y;
  const int b = b0 + bl;
  const int r = __builtin_amdgcn_readfirstlane(rgn[b]);
  sBias[tid] = bias[r * 128 + tid];
  const int oy0 = blockIdx.x * 4;
  const unsigned short* gbase = in + (size_t)bl * 8 * 66 * 66 * 8;
  const int lane = tid & 63, wv = tid >> 6;
  const int n = lane & 15, q = (lane >> 4) & 3;
  const short8* wpb = (const short8*)wp + (size_t)r * 9 * 2 * 8 * 64 + lane;
  floatx4 acc[4][8];
#pragma unroll
  for (int nt = 0; nt < 4; ++nt)
#pragma unroll
    for (int m = 0; m < 8; ++m) acc[nt][m] = (floatx4){0.f, 0.f, 0.f, 0.f};
#pragma unroll
  for (int s = 0; s < 2; ++s) {
    __syncthreads();  // previous phase's reads done before restage
    for (int seg = 0; seg < 2376; seg += 128) {
      int c = seg + tid;
      if (c < 2376) {
        int iy = c / 264;
        int rem = c - iy * 264;
        int c8 = rem / 66;
        int x = rem - c8 * 66;
        const unsigned short* gp =
            gbase + (((size_t)(s * 4 + c8) * 66 + 2 * oy0 + iy) * 66 + x) * 8;
        g2l16(gp, tile + (size_t)(seg + wv * 64) * 8);
      }
    }
    __syncthreads();
#pragma unroll
    for (int tap = 0; tap < 9; ++tap) {
      const int ky = tap / 3, kx = tap % 3;
      short8 afr[8];
#pragma unroll
      for (int m = 0; m < 8; ++m) afr[m] = wpb[((tap * 2 + s) * 8 + m) * 64];
      short8 bfr[4];
#pragma unroll
      for (int nt = 0; nt < 4; ++nt) {
        int oyl = 2 * wv + (nt >> 1);          // local out row 0..3
        int ox = ((nt & 1) << 4) + n;          // 0..31
        bfr[nt] = *(const short8*)&tile[(((2 * oyl + ky) * 4 + q) * 66 +
                                        (2 * ox + kx)) * 8];
      }
#pragma unroll
      for (int m = 0; m < 8; ++m)
#pragma unroll
        for (int nt = 0; nt < 4; ++nt)
          acc[nt][m] = __builtin_amdgcn_mfma_f32_16x16x32_bf16(afr[m], bfr[nt],
                                                               acc[nt][m], 0, 0, 0);
    }
  }
  // bias + ReLU + GAP: per-wave shfl reduce, LDS cross-wave combine
#pragma unroll
  for (int m = 0; m < 8; ++m)
#pragma unroll
    for (int rr = 0; rr < 4; ++rr) {
      float bv = sBias[m * 16 + q * 4 + rr];
      float vs = 0.f;
#pragma unroll
      for (int nt = 0; nt < 4; ++nt) {
        float v = acc[nt][m][rr] + bv;
        vs += (v > 0.f ? v : 0.f);
      }
      vs += __shfl_xor(vs, 1, 16);
      vs += __shfl_xor(vs, 2, 16);
      vs += __shfl_xor(vs, 4, 16);
      vs += __shfl_xor(vs, 8, 16);
      if (n == 0) sGap[wv * 128 + m * 16 + q * 4 + rr] = vs;
    }
  __syncthreads();
  atomicAdd(&feat[b * 128 + tid], sGap[tid] + sGap[128 + tid]);
}

__global__ __launch_bounds__(256) void head_k(
    const float* __restrict__ feat, const float* __restrict__ fw,
    const float* __restrict__ fb, const int* __restrict__ rgn,
    float* __restrict__ out) {
  int t = threadIdx.x;  // 128 samples x 2 classes
  int b = t >> 1, c = t & 1;
  int r = rgn[b];
  const float* fwr = fw + (r * 2 + c) * 128;
  const float* fv = feat + b * 128;
  float a = 0.f;
#pragma unroll 8
  for (int j = 0; j < 128; ++j) a = fmaf(fwr[j], fv[j], a);
  out[t] = a * (1.0f / 1024.0f) + fb[r * 2 + c];
}

extern "C" void kernel_launch(void* const* d_in, const int* in_sizes, int n_in,
                              void* d_out, int out_size, void* d_ws, size_t ws_size,
                              hipStream_t stream) {
  const float* img = (const float*)d_in[0];
  const int* rgn_raw = (const int*)d_in[1];
  const float* w1 = (const float*)d_in[2];
  const float* b1 = (const float*)d_in[3];
  const float* w2 = (const float*)d_in[4];
  const float* b2 = (const float*)d_in[5];
  const float* w3 = (const float*)d_in[6];
  const float* b3 = (const float*)d_in[7];
  const float* fw = (const float*)d_in[8];
  const float* fb = (const float*)d_in[9];
  float* out = (float*)d_out;

  const size_t h1p_s = (size_t)4 * 130 * 130 * 8 * 2;  // 1.08 MB
  const size_t h2p_s = (size_t)8 * 66 * 66 * 8 * 2;    // 557 KB
  const size_t per_sample = h1p_s + h2p_s;             // ~1.64 MB
  const size_t fixed = (size_t)16384 * 2 + (size_t)147456 * 2 +
                       (size_t)589824 * 2 + 128 * 128 * 4 + 512 + 16 * 256;
  int C = 128;
  while (C > 1 && fixed + (size_t)C * per_sample > ws_size) C >>= 1;

  char* ws = (char*)d_ws;
  size_t off = 0;
  auto alloc = [&](size_t bytes) {
    char* p = ws + off;
    off += (bytes + 255) & ~(size_t)255;
    return p;
  };
  unsigned short* h1p = (unsigned short*)alloc((size_t)C * h1p_s);
  unsigned short* h2p = (unsigned short*)alloc((size_t)C * h2p_s);
  unsigned short* w1p = (unsigned short*)alloc((size_t)16384 * 2);
  unsigned short* w2p = (unsigned short*)alloc((size_t)147456 * 2);
  unsigned short* w3p = (unsigned short*)alloc((size_t)589824 * 2);
  float* feat = (float*)alloc((size_t)128 * 128 * 4);
  int* rgn = (int*)alloc((size_t)128 * 4);

  hipLaunchKernelGGL(prep_k, dim3(1), dim3(128), 0, stream, rgn_raw, rgn, feat);
  hipLaunchKernelGGL(pack1_k, dim3(64), dim3(256), 0, stream, w1, w1p);
  hipLaunchKernelGGL((packT_k<64, 32, 1, 4>), dim3(576), dim3(256), 0, stream, w2, w2p);
  hipLaunchKernelGGL((packT_k<128, 64, 2, 8>), dim3(2304), dim3(256), 0, stream, w3, w3p);
  {  // zero halos (interiors rewritten every chunk)
    int n1 = C * 4 * (2 * 130 + 2 * 128);
    hipLaunchKernelGGL(halo8_k, dim3((n1 + 255) / 256), dim3(256), 0, stream,
                       h1p, C * 4, 130, 130);
    int n2 = C * 8 * (2 * 66 + 2 * 64);
    hipLaunchKernelGGL(halo8_k, dim3((n2 + 255) / 256), dim3(256), 0, stream,
                       h2p, C * 8, 66, 66);
  }

  for (int b0 = 0; b0 < 128; b0 += C) {
    // conv1 fused: 32 row-group blocks (4 rows x 128 px) per sample
    hipLaunchKernelGGL(conv1f_k, dim3(32, C), dim3(256), 0, stream,
                       img, w1p, b1, rgn, h1p, b0);
    // conv2: 16 row-group blocks (4 rows x 64 px each) per sample
    hipLaunchKernelGGL(conv2lds_k, dim3(16, C), dim3(256), 0, stream,
                       h1p, w2p, b2, rgn, h2p, b0);
    // conv3: 8 row-group blocks (4 rows x 32 px each) per sample, 128 thr
    hipLaunchKernelGGL(conv3lds_k, dim3(8, C), dim3(128), 0, stream,
                       h2p, w3p, b3, rgn, feat, b0);
  }
  hipLaunchKernelGGL(head_k, dim3(1), dim3(256), 0, stream, feat, fw, fb, rgn, out);
}

// Round 14
// 332.075 us; speedup vs baseline: 1.1181x; 1.0012x over previous
//
#include <hip/hip_runtime.h>
#include <cstdint>

// ---------------------------------------------------------------------------
// RegionModel R14: conv1f re-tiled + vectorized staging.
// R13's fused conv1 was 89us (27% HBM, occ 36%): 56 VGPR + 64 AGPR acc = 120
// regs capped it at 4 waves/SIMD, and staging was 9 latency-chained scalar
// rounds/thread. R14: block = 4 rows x 64 px (acc 32 AGPR -> ~88 regs -> 5
// blocks/CU), tile 9x130x4 = 9.4KB, staging = float4 x3 planes per 4px chunk
// (~1.1 rounds), x-strip halo loaded by 18 threads. conv2/conv3 unchanged
// from R12/R13 (channel-group-blocked layout, coalesced global_load_lds).
// ---------------------------------------------------------------------------

typedef __attribute__((ext_vector_type(8))) short short8;
typedef __attribute__((ext_vector_type(4))) float floatx4;
typedef __attribute__((ext_vector_type(4))) unsigned short ushort4v;
typedef __attribute__((ext_vector_type(4))) float float4v;
typedef __attribute__((ext_vector_type(2))) unsigned int uint2v;

__device__ inline unsigned short f2bf(float f) {
  union { float f; unsigned u; } x;
  x.f = f;
  unsigned u = x.u;
  u += 0x7FFFu + ((u >> 16) & 1u);  // round-to-nearest-even
  return (unsigned short)(u >> 16);
}

// Async 16B global->LDS DMA. LDS dest = wave-uniform base + lane*16.
__device__ inline void g2l16(const unsigned short* g, unsigned short* l) {
  __builtin_amdgcn_global_load_lds(
      (const __attribute__((address_space(1))) unsigned int*)g,
      (__attribute__((address_space(3))) unsigned int*)(unsigned int)(uintptr_t)l,
      16, 0, 0);
}

__global__ __launch_bounds__(128) void prep_k(const int* __restrict__ rp,
                                              int* __restrict__ rout,
                                              float* __restrict__ feat) {
  __shared__ int is64;
  if (threadIdx.x == 0) {
    int odd_or = 0;
    for (int i = 0; i < 64; ++i) odd_or |= rp[2 * i + 1];
    is64 = (odd_or == 0) ? 1 : 0;
  }
  __syncthreads();
  int b = threadIdx.x;
  int r = is64 ? rp[2 * b] : rp[b];
  rout[b] = r & 7;
  float* fr = feat + b * 128;
  for (int j = 0; j < 128; ++j) fr[j] = 0.f;
}

// conv1 weights -> [r][kg(2)][mt(2)][lane][j] ; k = kg*32+q*8+j maps to
// row = kg*2+(q>>1), idx=(q&1)*8+j, kx=idx>>2, c=idx&3; pad slots -> 0.
__global__ __launch_bounds__(256) void pack1_k(const float* __restrict__ w,
                                               unsigned short* __restrict__ dst) {
  int t = blockIdx.x * blockDim.x + threadIdx.x;
  if (t >= 16384) return;
  int j = t & 7, lane = (t >> 3) & 63, mt = (t >> 9) & 1, kg = (t >> 10) & 1,
      r = t >> 11;
  int oc = mt * 16 + (lane & 15);
  int q = (lane >> 4) & 3;
  int row = kg * 2 + (q >> 1);
  int idx = (q & 1) * 8 + j;
  int kx = idx >> 2, c = idx & 3;
  float val = 0.f;
  if (row < 3 && kx < 3 && c < 3) val = w[((r * 32 + oc) * 3 + c) * 9 + row * 3 + kx];
  dst[t] = f2bf(val);
}

// conv2/3 weights [R][OC][IC][3][3] -> [r][tap][s][mt][lane][j], ic=s*32+q*8+j
template <int OC, int IC, int SUBK, int MTG>
__global__ __launch_bounds__(256) void packT_k(const float* __restrict__ w,
                                               unsigned short* __restrict__ dst) {
  const int total = 8 * 9 * SUBK * MTG * 512;
  int t = blockIdx.x * blockDim.x + threadIdx.x;
  if (t >= total) return;
  int j = t & 7, lane = (t >> 3) & 63;
  int u = t >> 9;
  int mt = u % MTG; u /= MTG;
  int s = u % SUBK; u /= SUBK;
  int tap = u % 9;
  int r = u / 9;
  int oc = mt * 16 + (lane & 15);
  int ic = s * 32 + ((lane >> 4) & 3) * 8 + j;
  dst[t] = f2bf(w[((r * OC + oc) * IC + ic) * 9 + tap]);
}

// zero halo of channel-group plane buffer [nplane][HP][WP][8]
__global__ __launch_bounds__(256) void halo8_k(unsigned short* __restrict__ buf,
                                               int nplane, int HP, int WP) {
  int per = 2 * WP + 2 * (HP - 2);
  int t = blockIdx.x * blockDim.x + threadIdx.x;
  if (t >= nplane * per) return;
  int s = t / per, i = t - s * per;
  int y, x;
  if (i < WP) { y = 0; x = i; }
  else if (i < 2 * WP) { y = HP - 1; x = i - WP; }
  else {
    int ii = i - 2 * WP;
    y = 1 + (ii >> 1);
    x = (ii & 1) ? (WP - 1) : 0;
  }
  short8 z = {0, 0, 0, 0, 0, 0, 0, 0};
  *(short8*)(buf + ((size_t)s * HP * WP + y * WP + x) * 8) = z;
}

// conv1 FUSED: fp32 planar img -> bf16 LDS tile [9][130][4] -> MFMA.
// Block = 4 out rows x 64 px (grid 2 x 32 x C); wave = 1 row, 4 n-tiles.
// acc[4][2] = 32 AGPR -> ~88 unified regs -> 5 blocks/CU natural.
// Output h1p layout [c8=4][130][130][8].
__global__ __launch_bounds__(256, 4) void conv1f_k(
    const float* __restrict__ img, const unsigned short* __restrict__ wp,
    const float* __restrict__ bias, const int* __restrict__ rgn,
    unsigned short* __restrict__ outp, int b0) {
  __shared__ unsigned short tile[9 * 130 * 4];  // 9,360 B
  __shared__ float sBias[32];
  const int tid = threadIdx.x;
  const int bl = blockIdx.z;
  const int r = __builtin_amdgcn_readfirstlane(rgn[b0 + bl]);
  if (tid < 32) sBias[tid] = bias[r * 32 + tid];
  const int oy0 = blockIdx.y * 4;
  const int ox0 = blockIdx.x * 64;
  const float* ib = img + (size_t)(b0 + bl) * 3 * 65536;
  // x-strip halo (tile x = 0 and 129): real data at the x-half boundary
  if (tid < 18) {
    int tr = tid >> 1, side = tid & 1;
    int tx = side ? 129 : 0;
    int ur = 2 * oy0 + tr - 1;
    int uc = 2 * ox0 + (side ? 128 : -1);
    ushort4v v = {0, 0, 0, 0};
    if ((unsigned)ur < 256u && (unsigned)uc < 256u) {
      const float* p = ib + ur * 256 + uc;
      v.x = f2bf(p[0]);
      v.y = f2bf(p[65536]);
      v.z = f2bf(p[131072]);
    }
    *(ushort4v*)&tile[(size_t)(tr * 130 + tx) * 4] = v;
  }
  // interior: 288 chunks of 4 px (tile x = 1+4*xq .. 4+4*xq)
  for (int seg = 0; seg < 288; seg += 256) {
    int c = seg + tid;
    if (c < 288) {
      int tr = c >> 5, xq = c & 31;
      int ur = 2 * oy0 + tr - 1;
      unsigned short* dp = &tile[(size_t)(tr * 130 + 1 + 4 * xq) * 4];
      if ((unsigned)ur < 256u) {
        const float* p = ib + ur * 256 + 2 * ox0 + 4 * xq;
        float4v a = *(const float4v*)p;
        float4v bb = *(const float4v*)(p + 65536);
        float4v cc = *(const float4v*)(p + 131072);
#pragma unroll
        for (int i = 0; i < 4; ++i) {
          ushort4v v = {f2bf(a[i]), f2bf(bb[i]), f2bf(cc[i]), 0};
          *(ushort4v*)(dp + i * 4) = v;
        }
      } else {
        ushort4v z = {0, 0, 0, 0};
#pragma unroll
        for (int i = 0; i < 4; ++i) *(ushort4v*)(dp + i * 4) = z;
      }
    }
  }
  __syncthreads();
  const int n = tid & 15, q = (tid >> 4) & 3, w = tid >> 6;
  const int lane = tid & 63;
  const short8* wpb = (const short8*)wp + (size_t)r * 256 + lane;
  short8 afr[2][2];
#pragma unroll
  for (int kg = 0; kg < 2; ++kg)
#pragma unroll
    for (int m = 0; m < 2; ++m) afr[kg][m] = wpb[(kg * 2 + m) * 64];
  floatx4 acc[4][2];
#pragma unroll
  for (int nt = 0; nt < 4; ++nt)
#pragma unroll
    for (int m = 0; m < 2; ++m) acc[nt][m] = (floatx4){0.f, 0.f, 0.f, 0.f};
#pragma unroll
  for (int kg = 0; kg < 2; ++kg) {
    int row = kg * 2 + (q >> 1);
    int rowc = (row < 3) ? row : 0;  // pad row: zero weights, safe addr
    int tr = 2 * w + rowc;           // 0..8
#pragma unroll
    for (int nt = 0; nt < 4; ++nt) {
      int lx = nt * 16 + n;  // local out px 0..63
      short8 bfr =
          *(const short8*)&tile[((size_t)tr * 130 + 2 * lx) * 4 + (q & 1) * 8];
#pragma unroll
      for (int m = 0; m < 2; ++m)
        acc[nt][m] =
            __builtin_amdgcn_mfma_f32_16x16x32_bf16(afr[kg][m], bfr, acc[nt][m], 0, 0, 0);
    }
  }
  unsigned short* ob = outp + (size_t)bl * 4 * 130 * 130 * 8;
  const int oy = oy0 + w;
#pragma unroll
  for (int nt = 0; nt < 4; ++nt) {
    int ox = ox0 + nt * 16 + n;
#pragma unroll
    for (int m = 0; m < 2; ++m) {
      ushort4v st;
#pragma unroll
      for (int rr = 0; rr < 4; ++rr) {
        float v = acc[nt][m][rr] + sBias[m * 16 + q * 4 + rr];
        st[rr] = f2bf(v > 0.f ? v : 0.f);
      }
      int cg = m * 2 + (q >> 1);  // oc/8
      *(ushort4v*)(ob + (((size_t)cg * 130 + oy + 1) * 130 + ox + 1) * 8 +
                   (q & 1) * 4) = st;
    }
  }
}

// conv2: 32->64, 64x64 out. Block = 4 out rows x 64 px. h1p [c8=4][130][130][8].
// LDS tile [row][c8][x][8] = chunk c*16B; global chunk run contiguous in x.
__global__ __launch_bounds__(256, 2) void conv2lds_k(
    const unsigned short* __restrict__ in, const unsigned short* __restrict__ wp,
    const float* __restrict__ bias, const int* __restrict__ rgn,
    unsigned short* __restrict__ outp, int b0) {
  __shared__ unsigned short tile[9 * 4 * 130 * 8];  // 74,880 B
  __shared__ float sBias[64];
  const int tid = threadIdx.x;
  const int bl = blockIdx.y;
  const int r = __builtin_amdgcn_readfirstlane(rgn[b0 + bl]);
  if (tid < 64) sBias[tid] = bias[r * 64 + tid];
  const int oy0 = blockIdx.x * 4;
  const int wv = tid >> 6;
  const unsigned short* gsrc = in + (size_t)bl * 4 * 130 * 130 * 8;
  for (int seg = 0; seg < 4680; seg += 256) {
    int c = seg + tid;
    if (c < 4680) {
      int row = c / 520;
      int rem = c - row * 520;
      int c8 = rem / 130;
      int x = rem - c8 * 130;
      const unsigned short* gp =
          gsrc + (((size_t)c8 * 130 + 2 * oy0 + row) * 130 + x) * 8;
      g2l16(gp, tile + (size_t)(seg + wv * 64) * 8);
    }
  }
  __syncthreads();
  const int n = tid & 15, q = (tid >> 4) & 3, w = tid >> 6;
  const short8* wpb = (const short8*)wp + (size_t)r * 9 * 4 * 64 + (tid & 63);
  floatx4 acc[4][4];
#pragma unroll
  for (int nt = 0; nt < 4; ++nt)
#pragma unroll
    for (int m = 0; m < 4; ++m) acc[nt][m] = (floatx4){0.f, 0.f, 0.f, 0.f};
#pragma unroll
  for (int tap = 0; tap < 9; ++tap) {
    const int ky = tap / 3, kx = tap % 3;
    short8 afr[4];
#pragma unroll
    for (int m = 0; m < 4; ++m) afr[m] = wpb[(tap * 4 + m) * 64];
    short8 bfr[4];
#pragma unroll
    for (int nt = 0; nt < 4; ++nt) {
      int ox = nt * 16 + n;
      bfr[nt] = *(const short8*)&tile[((((2 * w + ky) << 2) + q) * 130 +
                                      (2 * ox + kx)) * 8];
    }
#pragma unroll
    for (int m = 0; m < 4; ++m)
#pragma unroll
      for (int nt = 0; nt < 4; ++nt)
        acc[nt][m] = __builtin_amdgcn_mfma_f32_16x16x32_bf16(afr[m], bfr[nt],
                                                             acc[nt][m], 0, 0, 0);
  }
  unsigned short* ob = outp + (size_t)bl * 8 * 66 * 66 * 8;
  const int oy = oy0 + w;
#pragma unroll
  for (int nt = 0; nt < 4; ++nt) {
    int ox = nt * 16 + n;
#pragma unroll
    for (int m = 0; m < 4; ++m) {
      ushort4v st;
#pragma unroll
      for (int rr = 0; rr < 4; ++rr) {
        float v = acc[nt][m][rr] + sBias[m * 16 + q * 4 + rr];
        st[rr] = f2bf(v > 0.f ? v : 0.f);
      }
      int cg = m * 2 + (q >> 1);  // oc/8
      *(ushort4v*)(ob + (((size_t)cg * 66 + oy + 1) * 66 + ox + 1) * 8 +
                   (q & 1) * 4) = st;
    }
  }
}

// conv3: 64->128, 32x32 out, fused bias+ReLU+GAP. h2p [c8=8][66][66][8].
// Block = 128 thr (2 waves), 4 out rows x 32 px, all 128 oc (acc 128 AGPR).
// Two 32-ch K-phases; tile [iy][c8][x][8] = 38,016 B; chunks contiguous in x.
__global__ __launch_bounds__(128, 2) void conv3lds_k(
    const unsigned short* __restrict__ in, const unsigned short* __restrict__ wp,
    const float* __restrict__ bias, const int* __restrict__ rgn,
    float* __restrict__ feat, int b0) {
  __shared__ unsigned short tile[9 * 4 * 66 * 8];  // 38,016 B
  __shared__ float sBias[128];
  __shared__ float sGap[2 * 128];
  const int tid = threadIdx.x;
  const int bl = blockIdx.y;
  const int b = b0 + bl;
  const int r = __builtin_amdgcn_readfirstlane(rgn[b]);
  sBias[tid] = bias[r * 128 + tid];
  const int oy0 = blockIdx.x * 4;
  const unsigned short* gbase = in + (size_t)bl * 8 * 66 * 66 * 8;
  const int lane = tid & 63, wv = tid >> 6;
  const int n = lane & 15, q = (lane >> 4) & 3;
  const short8* wpb = (const short8*)wp + (size_t)r * 9 * 2 * 8 * 64 + lane;
  floatx4 acc[4][8];
#pragma unroll
  for (int nt = 0; nt < 4; ++nt)
#pragma unroll
    for (int m = 0; m < 8; ++m) acc[nt][m] = (floatx4){0.f, 0.f, 0.f, 0.f};
#pragma unroll
  for (int s = 0; s < 2; ++s) {
    __syncthreads();  // previous phase's reads done before restage
    for (int seg = 0; seg < 2376; seg += 128) {
      int c = seg + tid;
      if (c < 2376) {
        int iy = c / 264;
        int rem = c - iy * 264;
        int c8 = rem / 66;
        int x = rem - c8 * 66;
        const unsigned short* gp =
            gbase + (((size_t)(s * 4 + c8) * 66 + 2 * oy0 + iy) * 66 + x) * 8;
        g2l16(gp, tile + (size_t)(seg + wv * 64) * 8);
      }
    }
    __syncthreads();
#pragma unroll
    for (int tap = 0; tap < 9; ++tap) {
      const int ky = tap / 3, kx = tap % 3;
      short8 afr[8];
#pragma unroll
      for (int m = 0; m < 8; ++m) afr[m] = wpb[((tap * 2 + s) * 8 + m) * 64];
      short8 bfr[4];
#pragma unroll
      for (int nt = 0; nt < 4; ++nt) {
        int oyl = 2 * wv + (nt >> 1);          // local out row 0..3
        int ox = ((nt & 1) << 4) + n;          // 0..31
        bfr[nt] = *(const short8*)&tile[(((2 * oyl + ky) * 4 + q) * 66 +
                                        (2 * ox + kx)) * 8];
      }
#pragma unroll
      for (int m = 0; m < 8; ++m)
#pragma unroll
        for (int nt = 0; nt < 4; ++nt)
          acc[nt][m] = __builtin_amdgcn_mfma_f32_16x16x32_bf16(afr[m], bfr[nt],
                                                               acc[nt][m], 0, 0, 0);
    }
  }
  // bias + ReLU + GAP: per-wave shfl reduce, LDS cross-wave combine
#pragma unroll
  for (int m = 0; m < 8; ++m)
#pragma unroll
    for (int rr = 0; rr < 4; ++rr) {
      float bv = sBias[m * 16 + q * 4 + rr];
      float vs = 0.f;
#pragma unroll
      for (int nt = 0; nt < 4; ++nt) {
        float v = acc[nt][m][rr] + bv;
        vs += (v > 0.f ? v : 0.f);
      }
      vs += __shfl_xor(vs, 1, 16);
      vs += __shfl_xor(vs, 2, 16);
      vs += __shfl_xor(vs, 4, 16);
      vs += __shfl_xor(vs, 8, 16);
      if (n == 0) sGap[wv * 128 + m * 16 + q * 4 + rr] = vs;
    }
  __syncthreads();
  atomicAdd(&feat[b * 128 + tid], sGap[tid] + sGap[128 + tid]);
}

__global__ __launch_bounds__(256) void head_k(
    const float* __restrict__ feat, const float* __restrict__ fw,
    const float* __restrict__ fb, const int* __restrict__ rgn,
    float* __restrict__ out) {
  int t = threadIdx.x;  // 128 samples x 2 classes
  int b = t >> 1, c = t & 1;
  int r = rgn[b];
  const float* fwr = fw + (r * 2 + c) * 128;
  const float* fv = feat + b * 128;
  float a = 0.f;
#pragma unroll 8
  for (int j = 0; j < 128; ++j) a = fmaf(fwr[j], fv[j], a);
  out[t] = a * (1.0f / 1024.0f) + fb[r * 2 + c];
}

extern "C" void kernel_launch(void* const* d_in, const int* in_sizes, int n_in,
                              void* d_out, int out_size, void* d_ws, size_t ws_size,
                              hipStream_t stream) {
  const float* img = (const float*)d_in[0];
  const int* rgn_raw = (const int*)d_in[1];
  const float* w1 = (const float*)d_in[2];
  const float* b1 = (const float*)d_in[3];
  const float* w2 = (const float*)d_in[4];
  const float* b2 = (const float*)d_in[5];
  const float* w3 = (const float*)d_in[6];
  const float* b3 = (const float*)d_in[7];
  const float* fw = (const float*)d_in[8];
  const float* fb = (const float*)d_in[9];
  float* out = (float*)d_out;

  const size_t h1p_s = (size_t)4 * 130 * 130 * 8 * 2;  // 1.08 MB
  const size_t h2p_s = (size_t)8 * 66 * 66 * 8 * 2;    // 557 KB
  const size_t per_sample = h1p_s + h2p_s;             // ~1.64 MB
  const size_t fixed = (size_t)16384 * 2 + (size_t)147456 * 2 +
                       (size_t)589824 * 2 + 128 * 128 * 4 + 512 + 16 * 256;
  int C = 128;
  while (C > 1 && fixed + (size_t)C * per_sample > ws_size) C >>= 1;

  char* ws = (char*)d_ws;
  size_t off = 0;
  auto alloc = [&](size_t bytes) {
    char* p = ws + off;
    off += (bytes + 255) & ~(size_t)255;
    return p;
  };
  unsigned short* h1p = (unsigned short*)alloc((size_t)C * h1p_s);
  unsigned short* h2p = (unsigned short*)alloc((size_t)C * h2p_s);
  unsigned short* w1p = (unsigned short*)alloc((size_t)16384 * 2);
  unsigned short* w2p = (unsigned short*)alloc((size_t)147456 * 2);
  unsigned short* w3p = (unsigned short*)alloc((size_t)589824 * 2);
  float* feat = (float*)alloc((size_t)128 * 128 * 4);
  int* rgn = (int*)alloc((size_t)128 * 4);

  hipLaunchKernelGGL(prep_k, dim3(1), dim3(128), 0, stream, rgn_raw, rgn, feat);
  hipLaunchKernelGGL(pack1_k, dim3(64), dim3(256), 0, stream, w1, w1p);
  hipLaunchKernelGGL((packT_k<64, 32, 1, 4>), dim3(576), dim3(256), 0, stream, w2, w2p);
  hipLaunchKernelGGL((packT_k<128, 64, 2, 8>), dim3(2304), dim3(256), 0, stream, w3, w3p);
  {  // zero halos (interiors rewritten every chunk)
    int n1 = C * 4 * (2 * 130 + 2 * 128);
    hipLaunchKernelGGL(halo8_k, dim3((n1 + 255) / 256), dim3(256), 0, stream,
                       h1p, C * 4, 130, 130);
    int n2 = C * 8 * (2 * 66 + 2 * 64);
    hipLaunchKernelGGL(halo8_k, dim3((n2 + 255) / 256), dim3(256), 0, stream,
                       h2p, C * 8, 66, 66);
  }

  for (int b0 = 0; b0 < 128; b0 += C) {
    // conv1 fused: grid (x-half, row-group, sample) = (2, 32, C)
    hipLaunchKernelGGL(conv1f_k, dim3(2, 32, C), dim3(256), 0, stream,
                       img, w1p, b1, rgn, h1p, b0);
    // conv2: 16 row-group blocks (4 rows x 64 px each) per sample
    hipLaunchKernelGGL(conv2lds_k, dim3(16, C), dim3(256), 0, stream,
                       h1p, w2p, b2, rgn, h2p, b0);
    // conv3: 8 row-group blocks (4 rows x 32 px each) per sample, 128 thr
    hipLaunchKernelGGL(conv3lds_k, dim3(8, C), dim3(128), 0, stream,
                       h2p, w3p, b3, rgn, feat, b0);
  }
  hipLaunchKernelGGL(head_k, dim3(1), dim3(256), 0, stream, feat, fw, fb, rgn, out);
}